// Round 7
// baseline (119.776 us; speedup 1.0000x reference)
//
#include <hip/hip_runtime.h>
#include <hip/hip_fp16.h>
#include <stdint.h>

// x[16384,2048] f32, w[2048,2048] f32, bias[2048] f32, scalar scales.
// M=16384, N=2048, K=2048. Output f16 values stored as f32.
#define MDIM 16384
#define NDIM 2048
#define KDIM 2048

typedef __attribute__((ext_vector_type(4))) float f32x4;
typedef __attribute__((ext_vector_type(4))) int   i32x4;
typedef __attribute__((ext_vector_type(8))) int   i32x8;

// ---------------------------------------------------------------------------
// Bit-exact f32 -> e4m3fn (OCP) RTNE after clip to +-448.
// ---------------------------------------------------------------------------
__device__ __forceinline__ unsigned f32_to_e4m3(float x) {
    float q = fminf(448.f, fmaxf(-448.f, x));
    unsigned ub = __float_as_uint(q);
    unsigned sgn = (ub >> 24) & 0x80u;
    float aq = fabsf(q);
    int E = (int)((__float_as_uint(aq) >> 23) & 0xff) - 127;
    if (E < -6) E = -6;
    float rq = __uint_as_float((unsigned)(130 - E) << 23);  // 2^(3-E), exact
    int m = (int)rintf(aq * rq);                            // RTNE, exact scale
    if (m == 16) { m = 8; E += 1; }
    unsigned bits;
    if (m < 8) bits = sgn | (unsigned)m;
    else       bits = sgn | ((unsigned)(E + 7) << 3) | (unsigned)(m - 8);
    return bits;
}

__device__ __forceinline__ void quant_span(const float* __restrict__ x,
                                           uint8_t* __restrict__ q, float sc,
                                           unsigned i0, unsigned stride,
                                           unsigned n16) {
    for (unsigned i = i0; i < n16; i += stride) {
        const float4* xp = (const float4*)(x + (size_t)i * 16);
        uint32_t w[4];
#pragma unroll
        for (int j = 0; j < 4; ++j) {
            float4 v = xp[j];
            unsigned b0 = f32_to_e4m3(v.x / sc);
            unsigned b1 = f32_to_e4m3(v.y / sc);
            unsigned b2 = f32_to_e4m3(v.z / sc);
            unsigned b3 = f32_to_e4m3(v.w / sc);
            w[j] = b0 | (b1 << 8) | (b2 << 16) | (b3 << 24);
        }
        ((uint4*)q)[i] = make_uint4(w[0], w[1], w[2], w[3]);
    }
}

// Single dispatch: blocks [0,2048) quantize x, [2048,2304) quantize w.
__global__ void quant_both_kernel(const float* __restrict__ x,
                                  uint8_t* __restrict__ xq,
                                  const float* __restrict__ w,
                                  uint8_t* __restrict__ wq,
                                  const float* __restrict__ s_in,
                                  const float* __restrict__ s_w) {
    if (blockIdx.x < 2048) {
        unsigned i0 = blockIdx.x * blockDim.x + threadIdx.x;
        quant_span(x, xq, s_in[0], i0, 2048 * 256,
                   (unsigned)((size_t)MDIM * KDIM / 16));
    } else {
        unsigned i0 = (blockIdx.x - 2048) * blockDim.x + threadIdx.x;
        quant_span(w, wq, s_w[0], i0, 256 * 256,
                   (unsigned)((size_t)NDIM * KDIM / 16));
    }
}

// ---------------------------------------------------------------------------
// GEMM: C[M][N] = Aq[M][K] * Bq[N][K]^T, fp8 e4m3, via
// mfma_scale_f32_16x16x128_f8f6f4, unit scales (exact, 2x fp8 rate).
//
// 256x256 tile, BK=128B, 16 K-tiles, 8 waves (2Mx4N), 128KiB LDS dbuf.
// 4-phase fine-interleaved schedule (m201-style, m196: fine interleave is
// the lever). Per tile t (buf = t&1, obuf = other):
//   P0: read af0-3(mh0) 8 + bf0-1 4; stage A0,B1(t+1)->obuf; MFMA m0-3xn0-1
//   P1: read bf2-3 4;               stage B0(t+1)->obuf;     MFMA m0-3xn2-3
//       vmcnt(6)  [lands A1(t)];  barrier
//   P2: read af4-7(mh1) 8;                                   MFMA m4-7xn0-1
//   P3:                             stage A1(t+1)->obuf;     MFMA m4-7xn2-3
//       vmcnt(2)  [lands A0,B1,B0(t+1)];  barrier
// 2 barriers + 2 counted waits per tile; every unit has >=2-phase cover.
// Write-after-read audit: each obuf region's last read (tile t-1) is >=1
// barrier before its overwrite in tile t (A0:P0/P0, B1:P1/P0, B0:P1/P1,
// A1:P2/P3). FIFO: entering P0(t) only A1(t) outstanding.
//
// Chunk swizzle per 128B row (8x16B): phys pc = ((c+r)&7); linear gload_lds
// dest, inverse perm on global src, same perm on fragment reads (2-way
// residual only, measured rounds 4-6).
//
// Epilogue: rounded f16-as-f32 values staged through a [128][256] f32 LDS
// slab (reuses the 128KiB, K-loop done), stores become full-1KiB
// global_store_dwordx4 rows (vs 64B-granule scattered dwords).
// ---------------------------------------------------------------------------
#define BM 256
#define BN 256
#define BKB 128
#define NKT (KDIM / BKB)   // 16

__device__ __forceinline__ void gload_lds16(const uint8_t* g, uint8_t* l) {
    __builtin_amdgcn_global_load_lds(
        (const __attribute__((address_space(1))) void*)g,
        (__attribute__((address_space(3))) void*)l, 16, 0, 0);
}

__device__ __forceinline__ void barrier_fenced() {
    asm volatile("" ::: "memory");
    __builtin_amdgcn_s_barrier();
    asm volatile("" ::: "memory");
}

__global__ __launch_bounds__(512) void gemm_fp8_kernel(
    const uint8_t* __restrict__ Aq, const uint8_t* __restrict__ Bq,
    const float* __restrict__ bias, const float* __restrict__ s_in,
    const float* __restrict__ s_w, float* __restrict__ out) {

    extern __shared__ uint8_t lds[];   // 131072 B: 2x64KiB dbuf / f32[128][256]

    // XCD-aware bijective swizzle (nwg = 512, divisible by 8)
    int nwg = gridDim.x;
    int cpx = nwg >> 3;
    int bid = blockIdx.x;
    int swz = (bid & 7) * cpx + (bid >> 3);
    int tm = swz >> 3;                 // tiles_n = 8
    int tn = swz & 7;
    int row0 = tm * BM;
    int col0 = tn * BN;

    int tid  = threadIdx.x;
    int lane = tid & 63;
    int wid  = tid >> 6;
    int wr = wid >> 2, wc = wid & 3;   // 2M x 4N
    int r15 = lane & 15;
    int g   = lane >> 4;

    // fragment-read swizzle offsets (bytes within a row's 8 chunks)
    int perm0 = ((2 * g + r15) & 7) << 4;
    int perm1 = ((2 * g + 1 + r15) & 7) << 4;

    // ---- staging coordinates: unit = 1024 chunks (128 rows), 2 per thread --
    int pj[2] = {tid, 512 + tid};
    int rj[2], cj[2];
#pragma unroll
    for (int j = 0; j < 2; ++j) {
        rj[j] = pj[j] >> 3;
        cj[j] = ((pj[j] & 7) - (rj[j] & 7)) & 7;
    }
    size_t asrcoff[2], bsrcoff[2];
    int    adst[2], bdst[2];
#pragma unroll
    for (int j = 0; j < 2; ++j) {
        int ar = (rj[j] & 63) + ((rj[j] >> 6) << 7);   // A row interleave
        asrcoff[j] = (size_t)ar * KDIM + cj[j] * 16;
        bsrcoff[j] = (size_t)rj[j] * KDIM + cj[j] * 16;
        adst[j] = pj[j] * 16;             // + U*16384
        bdst[j] = 32768 + pj[j] * 16;     // + U*16384
    }

    const uint8_t* Asrc = Aq + (size_t)row0 * KDIM;
    const uint8_t* Bsrc = Bq + (size_t)col0 * KDIM;

#define STAGE_A(U, KT, DST)                                                   \
    {                                                                         \
        _Pragma("unroll")                                                     \
        for (int j_ = 0; j_ < 2; ++j_)                                        \
            gload_lds16(Asrc + asrcoff[j_] + (size_t)(U) * 64 * KDIM +        \
                            (size_t)(KT) * BKB,                               \
                        (DST) + adst[j_] + (U) * 16384);                      \
    }
#define STAGE_B(U, KT, DST)                                                   \
    {                                                                         \
        _Pragma("unroll")                                                     \
        for (int j_ = 0; j_ < 2; ++j_)                                        \
            gload_lds16(Bsrc + bsrcoff[j_] + (size_t)(U) * 128 * KDIM +       \
                            (size_t)(KT) * BKB,                               \
                        (DST) + bdst[j_] + (U) * 16384);                      \
    }

    f32x4 acc[8][4];
#pragma unroll
    for (int m = 0; m < 8; ++m)
#pragma unroll
        for (int n = 0; n < 4; ++n)
            acc[m][n] = (f32x4){0.f, 0.f, 0.f, 0.f};

    // ---- prologue: tile 0 units in FIFO order A0,B1,B0,A1; leave A1 ----
    {
        uint8_t* b0 = &lds[0];
        STAGE_A(0, 0, b0); STAGE_B(1, 0, b0); STAGE_B(0, 0, b0); STAGE_A(1, 0, b0);
        asm volatile("s_waitcnt vmcnt(2)" ::: "memory");
        barrier_fenced();
    }

    int aRowBase = wr * 64;                        // + m*16 + r15
    int bUnit = (wc >> 1) * 1024;
    int bRowBase = (wc & 1) * 64;                  // + n*16 + r15

    i32x8 bf[4], af[4];

#define LOAD_BF_H(bo, H)                                                      \
    _Pragma("unroll")                                                         \
    for (int n_ = 2 * (H); n_ < 2 * (H) + 2; ++n_) {                          \
        int rB = bRowBase + n_ * 16 + r15;                                    \
        const uint8_t* rp = lds + (bo) + 32768 + (bUnit + rB * 8) * 16;       \
        i32x4 lo = *(const i32x4*)(rp + perm0);                               \
        i32x4 hi = *(const i32x4*)(rp + perm1);                               \
        _Pragma("unroll")                                                     \
        for (int q_ = 0; q_ < 4; ++q_) { bf[n_][q_] = lo[q_]; bf[n_][4 + q_] = hi[q_]; } \
    }

#define LOAD_AF(bo, MH)                                                       \
    _Pragma("unroll")                                                         \
    for (int m_ = 0; m_ < 4; ++m_) {                                          \
        int rA = aRowBase + m_ * 16 + r15;                                    \
        const uint8_t* rp = lds + (bo) + ((MH) * 1024 + rA * 8) * 16;         \
        i32x4 lo = *(const i32x4*)(rp + perm0);                               \
        i32x4 hi = *(const i32x4*)(rp + perm1);                               \
        _Pragma("unroll")                                                     \
        for (int q_ = 0; q_ < 4; ++q_) { af[m_][q_] = lo[q_]; af[m_][4 + q_] = hi[q_]; } \
    }

#define MFMA_Q(MH, NH)                                                        \
    __builtin_amdgcn_s_setprio(1);                                            \
    _Pragma("unroll")                                                         \
    for (int m_ = 0; m_ < 4; ++m_)                                            \
        _Pragma("unroll")                                                     \
        for (int n_ = 2 * (NH); n_ < 2 * (NH) + 2; ++n_)                      \
            acc[(MH) * 4 + m_][n_] =                                          \
                __builtin_amdgcn_mfma_scale_f32_16x16x128_f8f6f4(             \
                    af[m_], bf[n_], acc[(MH) * 4 + m_][n_],                   \
                    0, 0, 0, 127, 0, 127);                                    \
    __builtin_amdgcn_s_setprio(0);

    for (int t = 0; t < NKT; ++t) {
        const unsigned bo = (unsigned)(t & 1) << 16;
        uint8_t* obuf = &lds[(unsigned)((t + 1) & 1) << 16];
        // ---- P0 ----
        LOAD_AF(bo, 0);
        LOAD_BF_H(bo, 0);
        if (t + 1 < NKT) { STAGE_A(0, t + 1, obuf); STAGE_B(1, t + 1, obuf); }
        MFMA_Q(0, 0);
        // ---- P1 ----
        LOAD_BF_H(bo, 1);
        if (t + 1 < NKT) { STAGE_B(0, t + 1, obuf); }
        MFMA_Q(0, 1);
        if (t + 1 < NKT) asm volatile("s_waitcnt vmcnt(6)" ::: "memory");
        else             asm volatile("s_waitcnt vmcnt(0)" ::: "memory");
        barrier_fenced();
        // ---- P2 ----
        LOAD_AF(bo, 1);
        MFMA_Q(1, 0);
        // ---- P3 ----
        if (t + 1 < NKT) { STAGE_A(1, t + 1, obuf); }
        MFMA_Q(1, 1);
        if (t + 1 < NKT) asm volatile("s_waitcnt vmcnt(2)" ::: "memory");
        barrier_fenced();
    }

    // ---- epilogue: f16 double-round + bias, LDS-transposed coalesced store -
    // slab = f32[128][256] over the (now dead) staging LDS.
    float s = s_in[0] * s_w[0];
    float* slab = (float*)lds;
    __half hb[4];
#pragma unroll
    for (int n = 0; n < 4; ++n)
        hb[n] = __float2half(bias[col0 + wc * 64 + n * 16 + r15]);

#pragma unroll
    for (int mh = 0; mh < 2; ++mh) {
        // write rounded values into the slab (slab row = wr*64 + m*16+g*4+r)
#pragma unroll
        for (int n = 0; n < 4; ++n) {
            int colb = wc * 64 + n * 16 + r15;
#pragma unroll
            for (int m = 0; m < 4; ++m) {
                int sr = wr * 64 + m * 16 + g * 4;
#pragma unroll
                for (int r = 0; r < 4; ++r) {
                    __half h = __float2half(acc[mh * 4 + m][n][r] * s);
                    slab[(sr + r) * 256 + colb] = __half2float(__hadd(h, hb[n]));
                }
            }
        }
        barrier_fenced();
        // store: wave wid covers slab rows [wid*16, wid*16+16), 1KiB per row
#pragma unroll
        for (int it = 0; it < 16; ++it) {
            int srow = wid * 16 + it;
            f32x4 vv = *(const f32x4*)&slab[srow * 256 + lane * 4];
            int grow = row0 + (srow >> 6) * 128 + mh * 64 + (srow & 63);
            *(f32x4*)&out[(size_t)grow * NDIM + col0 + lane * 4] = vv;
        }
        barrier_fenced();   // slab reads done before next mh overwrites
    }
#undef STAGE_A
#undef STAGE_B
#undef LOAD_BF_H
#undef LOAD_AF
#undef MFMA_Q
}

// ---------------------------------------------------------------------------
extern "C" void kernel_launch(void* const* d_in, const int* in_sizes, int n_in,
                              void* d_out, int out_size, void* d_ws, size_t ws_size,
                              hipStream_t stream) {
    const float* x      = (const float*)d_in[0];   // [16384, 2048]
    const float* weight = (const float*)d_in[1];   // [2048, 2048]
    const float* bias   = (const float*)d_in[2];   // [2048]
    const float* s_in   = (const float*)d_in[3];   // [1]
    const float* s_w    = (const float*)d_in[4];   // [1]
    float* out          = (float*)d_out;

    uint8_t* xq = (uint8_t*)d_ws;                          // 33.5 MB
    uint8_t* wq = (uint8_t*)d_ws + (size_t)MDIM * KDIM;    // 4.2 MB

    quant_both_kernel<<<2304, 256, 0, stream>>>(x, xq, weight, wq, s_in, s_w);

    dim3 grid((MDIM / BM) * (NDIM / BN));   // 64 * 8 = 512
    gemm_fp8_kernel<<<grid, 512, 131072, stream>>>(xq, wq, bias, s_in, s_w, out);
}